// Round 11
// baseline (125.974 us; speedup 1.0000x reference)
//
#include <hip/hip_runtime.h>

#define BATCH 16
#define C_IN  64
#define HH    64
#define WW    64
#define COUT  64
#define KK    9
#define HW    4096
#define CK    576
#define MROWB 208   // Mlds row stride bytes: 192 data + 16 pad (13 x 16 B)

typedef __bf16 bf16x8 __attribute__((ext_vector_type(8)));
typedef float  f32x16 __attribute__((ext_vector_type(16)));
typedef unsigned int u32x2 __attribute__((ext_vector_type(2)));

__device__ __forceinline__ unsigned int f32_to_bf16_rne(float f) {
    unsigned int b = __float_as_uint(f);
    b += 0x7FFFu + ((b >> 16) & 1u);
    return b >> 16;
}
__device__ __forceinline__ float bf16lo(unsigned int u) {
    return __uint_as_float(u << 16);
}
__device__ __forceinline__ float bf16hi(unsigned int u) {
    return __uint_as_float(u & 0xFFFF0000u);
}

// Fused prep.
//  blk <1024 : x (B,C,H,W) f32 -> xt (B,H,W,C) bf16
//  blk <1312 : w -> wt2, 32x32x16 A-frag order WITH channel-half split:
//      frag f = ((h2*3+kc)*6+ks)*2+ot ; wt2[(f*64+l)*8+j] =
//      W[o=ot*32+(l&31)][ c = h2*32 + (k_local&31), k = kc*3 + (k_local>>5) ]
//      where k_local = ks*16 + (l>>5)*8 + j  (in [0,96))
//  else      : d_out init to bias (atomic-reduce target for the 2 c-halves)
__global__ __launch_bounds__(256) void prep_kernel(
    const float* __restrict__ x, const float* __restrict__ w,
    const float* __restrict__ bias, unsigned short* __restrict__ xt,
    unsigned short* __restrict__ wt2, float* __restrict__ out) {
    const int t = threadIdx.x;
    const int blk = blockIdx.x;
    if (blk < 1024) {
        __shared__ unsigned short tile[64][72];
        const int b = blk >> 6, y = blk & 63;
        const float* xrow = x + ((b * 64) * 64 + y) * 64;
#pragma unroll
        for (int it = 0; it < 4; ++it) {
            const int idx = it * 256 + t;
            const int c = idx >> 4, seg = idx & 15;
            const float4 v = *(const float4*)(xrow + c * HW + seg * 4);
            tile[seg * 4 + 0][c] = (unsigned short)f32_to_bf16_rne(v.x);
            tile[seg * 4 + 1][c] = (unsigned short)f32_to_bf16_rne(v.y);
            tile[seg * 4 + 2][c] = (unsigned short)f32_to_bf16_rne(v.z);
            tile[seg * 4 + 3][c] = (unsigned short)f32_to_bf16_rne(v.w);
        }
        __syncthreads();
#pragma unroll
        for (int it = 0; it < 2; ++it) {
            const int idx = it * 256 + t;
            const int xx = idx >> 3, cs = idx & 7;
            *(int4*)&xt[((b * HW) + y * 64 + xx) * 64 + cs * 8] =
                *(const int4*)&tile[xx][cs * 8];
        }
    } else if (blk < 1312) {
        const int i = (blk - 1024) * 256 + t;   // 0..73727
        const int j = i & 7;
        const int l = (i >> 3) & 63;
        const int ot = (i >> 9) & 1;
        const int r = i >> 10;                  // 0..71
        const int ks = r % 6, kc = (r / 6) % 3, h2 = r / 18;
        const int o  = ot * 32 + (l & 31);
        const int kl = ks * 16 + (l >> 5) * 8 + j;   // 0..95
        const int tap = kl >> 5, c = h2 * 32 + (kl & 31);
        wt2[i] = (unsigned short)f32_to_bf16_rne(w[o * CK + c * KK + kc * 3 + tap]);
    } else {
        const int blkz = blk - 1312;            // 0..1023
#pragma unroll
        for (int it = 0; it < 4; ++it) {
            const int idx = blkz * 4096 + it * 1024 + t * 4;
            const float bv = bias[(idx >> 12) & 63];
            float4 v; v.x = bv; v.y = bv; v.z = bv; v.w = bv;
            *(float4*)(out + idx) = v;
        }
    }
}

// Main.  Block = 128 thr = 2 waves; wave = 32-px strip x 64 cout x 32
// CHANNELS (half).  R11 theory: per-CU L1-miss-throughput bound; the c-half
// split makes each corner-read exactly ONE 64-B line and halves the per-CU
// gather window (~28 KB, fits 32 KB L1) so the ~5x corner redundancy
// becomes L1 hits.  Swizzle gives each CU 8 adjacent rows of ONE image and
// ONE c-half.  Gathers: octet (8 lanes x 8 B) per corner; each lane
// accumulates all 4 corners of its own item across 4 instrs (no shuffles).
// Cross-half reduction: f32 atomicAdd onto bias-initialized d_out
// (commutative -> deterministic).  32x32x16 MFMA, K=96/chunk.
__global__ __launch_bounds__(128, 2) void dcn_main_kernel(
    const float* __restrict__ offset, const float* __restrict__ mask,
    const unsigned short* __restrict__ xt, const unsigned short* __restrict__ wt2,
    float* __restrict__ out) {
    __shared__ __align__(16) unsigned short Mlds[2][32 * (MROWB / 2)];
    __shared__ __align__(16) int PWw[2][288 * 4];
    __shared__ __align__(8) unsigned short PWa[2][288 * 4];

    const int t    = threadIdx.x;
    const int wave = __builtin_amdgcn_readfirstlane(t >> 6);
    const int lane = t & 63;
    const int oct  = lane >> 3, octl = lane & 7;
    const int n32  = lane & 31, h16 = lane >> 5;

    const int blk = blockIdx.x;
    const int xcd = blk & 7;                    // 2 images per XCD (R2)
    const int i8  = blk >> 3;                   // 0..255
    const int h2  = i8 & 1;                     // channel half (CU-uniform)
    const int s7  = i8 >> 1;                    // 0..127
    const int s   = ((s7 & 15) << 3) | (s7 >> 4);  // 8 adjacent rows / CU
    const int b   = (xcd << 1) | (s >> 6);
    const int row = s & 63;
    const int qb  = wave * 32;

    f32x16 acc[2];
#pragma unroll
    for (int ot = 0; ot < 2; ++ot)
#pragma unroll
        for (int r = 0; r < 16; ++r) acc[ot][r] = 0.f;

    const float* offb = offset + b * (2 * KK * HW) + row * 64;
    const float* mb   = mask + b * (KK * HW) + row * 64;
    // lane-constant part of gather address: image base + c-half + octet lane
    const char* xtbh  = (const char*)(xt + b * (HW * 64)) + h2 * 64 + octl * 8;
    char* MW = (char*)Mlds[wave];

    // ---- Prologue: params for 9 taps x 32 px = 288 items ----
#pragma unroll
    for (int it = 0; it < 5; ++it) {
        const int item = it * 64 + lane;
        if (item < 288) {
            const int tap = item >> 5, pxi = item & 31;
            const int ky = tap / 3, kx = tap - ky * 3;
            const int q = qb + pxi;
            const float oy = offb[(2 * tap) * HW + q];
            const float ox = offb[(2 * tap + 1) * HW + q];
            const float mk = mb[tap * HW + q];
            const float py  = oy + (float)(row - 1 + ky);
            const float pxf = ox + (float)(q - 1 + kx);
            const float y0f = floorf(py), x0f = floorf(pxf);
            const float wy = py - y0f, wx = pxf - x0f;
            const int y0 = (int)y0f, x0 = (int)x0f;
            const int y1 = y0 + 1,   x1 = x0 + 1;
            const float vy0 = (y0 >= 0 && y0 < HH) ? 1.f : 0.f;
            const float vy1 = (y1 >= 0 && y1 < HH) ? 1.f : 0.f;
            const float vx0 = (x0 >= 0 && x0 < WW) ? 1.f : 0.f;
            const float vx1 = (x1 >= 0 && x1 < WW) ? 1.f : 0.f;
            const float w00 = (1.f - wy) * (1.f - wx) * vy0 * vx0 * mk;
            const float w01 = (1.f - wy) * wx         * vy0 * vx1 * mk;
            const float w10 = wy * (1.f - wx)         * vy1 * vx0 * mk;
            const float w11 = wy * wx                 * vy1 * vx1 * mk;
            const int cy0 = min(max(y0, 0), HH - 1), cy1 = min(max(y1, 0), HH - 1);
            const int cx0 = min(max(x0, 0), WW - 1), cx1 = min(max(x1, 0), WW - 1);
            int4 P0;
            P0.x = __float_as_int(w00); P0.y = __float_as_int(w01);
            P0.z = __float_as_int(w10); P0.w = __float_as_int(w11);
            *(int4*)&PWw[wave][item * 4] = P0;
            ushort4 A;
            A.x = (unsigned short)(cy0 * 64 + cx0);
            A.y = (unsigned short)(cy0 * 64 + cx1);
            A.z = (unsigned short)(cy1 * 64 + cx0);
            A.w = (unsigned short)(cy1 * 64 + cx1);
            *(ushort4*)&PWa[wave][item * 4] = A;
        }
    }

    ushort4 a[12];
    u32x2 g[12][4];   // 48 in-flight one-line gathers (96 VGPR)

    for (int kc = 0; kc < 3; ++kc) {
        // ---- addresses (broadcast LDS reads), then issue all 48 gathers ----
#pragma unroll
        for (int grp = 0; grp < 12; ++grp)
            a[grp] = *(const ushort4*)&PWa[wave][(kc * 96 + grp * 8 + oct) * 4];
#pragma unroll
        for (int grp = 0; grp < 12; ++grp) {
            g[grp][0] = *(const u32x2*)(xtbh + ((int)a[grp].x << 7));
            g[grp][1] = *(const u32x2*)(xtbh + ((int)a[grp].y << 7));
            g[grp][2] = *(const u32x2*)(xtbh + ((int)a[grp].z << 7));
            g[grp][3] = *(const u32x2*)(xtbh + ((int)a[grp].w << 7));
        }
        // ---- blend: lane owns item grp*8+oct, 4 channels, all 4 corners ----
#pragma unroll
        for (int grp = 0; grp < 12; ++grp) {
            const int ic = grp * 8 + oct;          // within-chunk item
            const float4 w4 = *(const float4*)&PWw[wave][(kc * 96 + ic) * 4];
            const u32x2 u0 = g[grp][0], u1 = g[grp][1];
            const u32x2 u2 = g[grp][2], u3 = g[grp][3];
            float v0, v1, v2, v3;
            v0 = w4.x * bf16lo(u0.x);  v1 = w4.x * bf16hi(u0.x);
            v2 = w4.x * bf16lo(u0.y);  v3 = w4.x * bf16hi(u0.y);
            v0 = fmaf(w4.y, bf16lo(u1.x), v0);  v1 = fmaf(w4.y, bf16hi(u1.x), v1);
            v2 = fmaf(w4.y, bf16lo(u1.y), v2);  v3 = fmaf(w4.y, bf16hi(u1.y), v3);
            v0 = fmaf(w4.z, bf16lo(u2.x), v0);  v1 = fmaf(w4.z, bf16hi(u2.x), v1);
            v2 = fmaf(w4.z, bf16lo(u2.y), v2);  v3 = fmaf(w4.z, bf16hi(u2.y), v3);
            v0 = fmaf(w4.w, bf16lo(u3.x), v0);  v1 = fmaf(w4.w, bf16hi(u3.x), v1);
            v2 = fmaf(w4.w, bf16lo(u3.y), v2);  v3 = fmaf(w4.w, bf16hi(u3.y), v3);
            uint2 pk;
            pk.x = (f32_to_bf16_rne(v1) << 16) | f32_to_bf16_rne(v0);
            pk.y = (f32_to_bf16_rne(v3) << 16) | f32_to_bf16_rne(v2);
            const int tap = ic >> 5, pxi = ic & 31;
            *(uint2*)(MW + pxi * MROWB + tap * 64 + octl * 8) = pk;
        }
        // ---- MFMA: K=96 (3 taps x 32 ch), 6 K-steps x 2 o-tiles ----
#pragma unroll
        for (int ks = 0; ks < 6; ++ks) {
            const bf16x8 bfrag =
                *(const bf16x8*)(MW + n32 * MROWB + ks * 32 + h16 * 16);
#pragma unroll
            for (int ot = 0; ot < 2; ++ot) {
                const bf16x8 afrag = *(const bf16x8*)(
                    wt2 + (((((h2 * 3 + kc) * 6 + ks) << 1) + ot) << 9) + lane * 8);
                acc[ot] = __builtin_amdgcn_mfma_f32_32x32x16_bf16(afrag, bfrag,
                                                                  acc[ot], 0, 0, 0);
            }
        }
    }

    // ---- Epilogue: atomic-reduce the two c-halves onto bias-init'd out ----
    float* ob = out + b * (COUT * HW) + row * 64 + qb + n32;
#pragma unroll
    for (int ot = 0; ot < 2; ++ot)
#pragma unroll
        for (int r = 0; r < 16; ++r) {
            const int o = ot * 32 + (r & 3) + 8 * (r >> 2) + 4 * h16;
            atomicAdd(&ob[o * HW], acc[ot][r]);
        }
}

extern "C" void kernel_launch(void* const* d_in, const int* in_sizes, int n_in,
                              void* d_out, int out_size, void* d_ws,
                              size_t ws_size, hipStream_t stream) {
    const float* x    = (const float*)d_in[0];
    const float* off  = (const float*)d_in[1];
    const float* mask = (const float*)d_in[2];
    const float* w    = (const float*)d_in[3];
    const float* bias = (const float*)d_in[4];
    float* out = (float*)d_out;

    unsigned short* xt  = (unsigned short*)d_ws;                     // 8388608 B
    unsigned short* wt2 = (unsigned short*)((char*)d_ws + 8388608);  // 147456 B

    prep_kernel<<<1024 + 288 + 1024, 256, 0, stream>>>(x, w, bias, xt, wt2, out);
    dcn_main_kernel<<<2048, 128, 0, stream>>>(off, mask, xt, wt2, out);
}